// Round 14
// baseline (640.006 us; speedup 1.0000x reference)
//
#include <hip/hip_runtime.h>

#define HWD 262144   // H*W*D
#define WD  4096     // W*D

typedef unsigned short bf16_t;
typedef unsigned short u16;
struct __align__(8) us4 { unsigned short x, y, z, w; };

typedef __bf16 bf16x8 __attribute__((ext_vector_type(8)));
typedef float  f32x4  __attribute__((ext_vector_type(4)));

__device__ inline float b2f(unsigned short u) {
    return __uint_as_float(((unsigned int)u) << 16);
}
__device__ inline unsigned short f2b(float f) {
    unsigned int u = __float_as_uint(f);
    u += 0x7fff + ((u >> 16) & 1);          // round-to-nearest-even
    return (unsigned short)(u >> 16);
}

union FragU { us4 h[2]; bf16x8 v; };
__device__ inline bf16x8 ld8_a8(const u16* p) {   // 8B-aligned source
    FragU f; f.h[0] = *(const us4*)p; f.h[1] = *(const us4*)(p + 4); return f.v;
}
__device__ inline bf16x8 ld8_a16(const u16* p) {  // 16B-aligned source
    return *(const bf16x8*)p;
}

// exact hi/lo split of 8 floats into two bf16x8 (x = hi + lo to ~2^-17 rel)
struct HL { bf16x8 h, l; };
__device__ inline HL split8(const float* w8) {
    FragU H, L;
    unsigned short hh[8], ll[8];
#pragma unroll
    for (int t = 0; t < 8; ++t) {
        hh[t] = f2b(w8[t]);
        ll[t] = f2b(w8[t] - b2f(hh[t]));   // residual is fp32-exact (Sterbenz)
    }
    H.h[0].x = hh[0]; H.h[0].y = hh[1]; H.h[0].z = hh[2]; H.h[0].w = hh[3];
    H.h[1].x = hh[4]; H.h[1].y = hh[5]; H.h[1].z = hh[6]; H.h[1].w = hh[7];
    L.h[0].x = ll[0]; L.h[0].y = ll[1]; L.h[0].z = ll[2]; L.h[0].w = ll[3];
    L.h[1].x = ll[4]; L.h[1].y = ll[5]; L.h[1].z = ll[6]; L.h[1].w = ll[7];
    HL r; r.h = H.v; r.l = L.v; return r;
}

// -------- one-time weight hi/lo split into MFMA-fragment layout --------------
__global__ void prep_w_kernel(
    const float* __restrict__ Wv, const float* __restrict__ Wq,
    const float* __restrict__ Wk,
    u16* __restrict__ WSv, u16* __restrict__ WSq, u16* __restrict__ WSk)
{
    const int t = threadIdx.x;
    const float* W; u16* D; int m, ks;
    if (t < 512)      { W = Wv; D = WSv; m = t >> 2;          ks = t & 3; }
    else if (t < 576) { W = Wq; D = WSq; m = (t - 512) >> 2;  ks = t & 3; }
    else if (t < 640) { W = Wk; D = WSk; m = (t - 576) >> 2;  ks = t & 3; }
    else return;
#pragma unroll
    for (int j = 0; j < 32; ++j) {
        const float w = W[m * 128 + ks * 32 + j];
        const u16 h = f2b(w);
        const u16 l = f2b(w - b2f(h));          // Sterbenz-exact residual
        D[((m * 4 + ks) * 2 + 0) * 32 + j] = h;
        D[((m * 4 + ks) * 2 + 1) * 32 + j] = l;
    }
}

// -------- v = Wv·x + bv AND q = Wq·x + bq: 4 n-tiles/block, rolling prefetch -
// IDENTICAL per-element math to R11/R13. Tile t+1's 16 loads are issued into
// the OTHER register buffer before tile t's split/MFMA/store — explicit
// two-buffer liveness forces deep MLP; weights amortized over 4 tiles.
__global__ __launch_bounds__(512, 4) void conv_x_mfma(
    const float* __restrict__ x, const u16* __restrict__ WSv,
    const u16* __restrict__ WSq,
    const float* __restrict__ bv, const float* __restrict__ bq,
    bf16_t* __restrict__ v, bf16_t* __restrict__ q)
{
    __shared__ __align__(16) u16 Xh[64][136];   // [n][k]
    __shared__ __align__(16) u16 Xl[64][136];
    const int tid  = threadIdx.x;
    const int lane = tid & 63;
    const int wv   = tid >> 6;                 // wave 0..7
    const int lg = lane >> 4, lr = lane & 15;
    const int nb = blockIdx.x * 256;           // 4 tiles of 64
    const int m0 = wv * 16;

    auto issue = [&](float (*dst)[8], int n0) {
#pragma unroll
        for (int gi = 0; gi < 2; ++gi) {
            const int g = wv + gi * 8;
#pragma unroll
            for (int s = 0; s < 8; ++s)
                dst[gi][s] = x[(size_t)(g * 8 + s) * HWD + n0 + lane];
        }
    };
    float B0[2][8], B1[2][8];
    issue(B0, nb);                             // tile 0 loads in flight

    // ---- A-frags: 16B loads of pre-split weights (once per block) ----
    bf16x8 Ah[4], Al[4], Qh[4], Ql[4];
#pragma unroll
    for (int ks = 0; ks < 4; ++ks) {
        Ah[ks] = ld8_a16(&WSv[(((m0 + lr) * 4 + ks) * 2 + 0) * 32 + lg * 8]);
        Al[ks] = ld8_a16(&WSv[(((m0 + lr) * 4 + ks) * 2 + 1) * 32 + lg * 8]);
    }
    if (wv < 4) {
#pragma unroll
        for (int ks = 0; ks < 4; ++ks) {
            Qh[ks] = ld8_a16(&WSq[((lr * 4 + ks) * 2 + 0) * 32 + lg * 8]);
            Ql[ks] = ld8_a16(&WSq[((lr * 4 + ks) * 2 + 1) * 32 + lg * 8]);
        }
    }

#pragma unroll
    for (int t = 0; t < 4; ++t) {              // fully unrolled: buf idx static
        float (*cur)[8] = (t & 1) ? B1 : B0;
        float (*nxt)[8] = (t & 1) ? B0 : B1;
        const int n0 = nb + t * 64;
        if (t < 3) issue(nxt, n0 + 64);        // next tile in flight under compute

        // ---- split + stage current tile ----
#pragma unroll
        for (int gi = 0; gi < 2; ++gi) {
            const int g = wv + gi * 8;
            HL hl = split8(cur[gi]);
            *(bf16x8*)&Xh[lane][g * 8] = hl.h;
            *(bf16x8*)&Xl[lane][g * 8] = hl.l;
        }
        __syncthreads();

        f32x4 acc[4];
#pragma unroll
        for (int ns = 0; ns < 4; ++ns) acc[ns] = (f32x4){0.f, 0.f, 0.f, 0.f};
        f32x4 accq = (f32x4){0.f, 0.f, 0.f, 0.f};
#pragma unroll
        for (int ks = 0; ks < 4; ++ks) {
#pragma unroll
            for (int ns = 0; ns < 4; ++ns) {
                const bf16x8 Bh = ld8_a16(&Xh[ns * 16 + lr][ks * 32 + lg * 8]);
                const bf16x8 Bl = ld8_a16(&Xl[ns * 16 + lr][ks * 32 + lg * 8]);
                acc[ns] = __builtin_amdgcn_mfma_f32_16x16x32_bf16(Ah[ks], Bh, acc[ns], 0, 0, 0);
                acc[ns] = __builtin_amdgcn_mfma_f32_16x16x32_bf16(Ah[ks], Bl, acc[ns], 0, 0, 0);
                acc[ns] = __builtin_amdgcn_mfma_f32_16x16x32_bf16(Al[ks], Bh, acc[ns], 0, 0, 0);
                if (wv < 4 && ns == wv) {
                    accq = __builtin_amdgcn_mfma_f32_16x16x32_bf16(Qh[ks], Bh, accq, 0, 0, 0);
                    accq = __builtin_amdgcn_mfma_f32_16x16x32_bf16(Qh[ks], Bl, accq, 0, 0, 0);
                    accq = __builtin_amdgcn_mfma_f32_16x16x32_bf16(Ql[ks], Bh, accq, 0, 0, 0);
                }
            }
        }
#pragma unroll
        for (int ns = 0; ns < 4; ++ns)
#pragma unroll
            for (int r = 0; r < 4; ++r) {
                const int m = m0 + 4 * lg + r;
                v[(size_t)m * HWD + n0 + ns * 16 + lr] = f2b(acc[ns][r] + bv[m]);
            }
        if (wv < 4) {
#pragma unroll
            for (int r = 0; r < 4; ++r) {
                const int m = 4 * lg + r;
                q[(size_t)m * HWD + n0 + wv * 16 + lr] = f2b(accq[r] + bq[m]);
            }
        }
        __syncthreads();                       // LDS reused by next tile
    }
}

// -------- k = Wk·y + bk: 4 n-tiles/block, rolling prefetch -------------------
__global__ __launch_bounds__(256, 4) void conv_y_mfma(
    const float* __restrict__ y, const u16* __restrict__ WSk,
    const float* __restrict__ bk, bf16_t* __restrict__ k)
{
    __shared__ __align__(16) u16 Yh[64][136];
    __shared__ __align__(16) u16 Yl[64][136];
    const int tid  = threadIdx.x;
    const int lane = tid & 63;
    const int wv   = tid >> 6;                // 0..3 = n-subtile
    const int lg = lane >> 4, lr = lane & 15;
    const int nb = blockIdx.x * 256;
    const int n  = tid & 63;

    auto issue = [&](float (*dst)[8], int n0) {
#pragma unroll
        for (int gi = 0; gi < 4; ++gi) {
            const int g = (tid >> 6) * 4 + gi;
#pragma unroll
            for (int s = 0; s < 8; ++s)
                dst[gi][s] = y[(size_t)(g * 8 + s) * HWD + n0 + n];
        }
    };
    float B0[4][8], B1[4][8];
    issue(B0, nb);

    bf16x8 Ah[4], Al[4];
#pragma unroll
    for (int ks = 0; ks < 4; ++ks) {
        Ah[ks] = ld8_a16(&WSk[((lr * 4 + ks) * 2 + 0) * 32 + lg * 8]);
        Al[ks] = ld8_a16(&WSk[((lr * 4 + ks) * 2 + 1) * 32 + lg * 8]);
    }

#pragma unroll
    for (int t = 0; t < 4; ++t) {
        float (*cur)[8] = (t & 1) ? B1 : B0;
        float (*nxt)[8] = (t & 1) ? B0 : B1;
        const int n0 = nb + t * 64;
        if (t < 3) issue(nxt, n0 + 64);

#pragma unroll
        for (int gi = 0; gi < 4; ++gi) {
            const int g = (tid >> 6) * 4 + gi;
            HL hl = split8(cur[gi]);
            *(bf16x8*)&Yh[n][g * 8] = hl.h;
            *(bf16x8*)&Yl[n][g * 8] = hl.l;
        }
        __syncthreads();

        f32x4 acc = (f32x4){0.f, 0.f, 0.f, 0.f};
#pragma unroll
        for (int ks = 0; ks < 4; ++ks) {
            const bf16x8 Bh = ld8_a16(&Yh[wv * 16 + lr][ks * 32 + lg * 8]);
            const bf16x8 Bl = ld8_a16(&Yl[wv * 16 + lr][ks * 32 + lg * 8]);
            acc = __builtin_amdgcn_mfma_f32_16x16x32_bf16(Ah[ks], Bh, acc, 0, 0, 0);
            acc = __builtin_amdgcn_mfma_f32_16x16x32_bf16(Ah[ks], Bl, acc, 0, 0, 0);
            acc = __builtin_amdgcn_mfma_f32_16x16x32_bf16(Al[ks], Bh, acc, 0, 0, 0);
        }
#pragma unroll
        for (int r = 0; r < 4; ++r) {
            const int m = 4 * lg + r;
            k[(size_t)m * HWD + n0 + wv * 16 + lr] = f2b(acc[r] + bk[m]);
        }
        __syncthreads();
    }
}

// ------------- transpose (w<->d): dst[c][h][d][w] = src[c][h][w][d] ----------
__global__ __launch_bounds__(256) void t_wd_kernel(
    const bf16_t* __restrict__ src, bf16_t* __restrict__ dst)
{
    const int h = blockIdx.x, c = blockIdx.y;
    __shared__ bf16_t tile[64][72];
    const size_t base = (size_t)c * HWD + h * WD;
    const int tid = threadIdx.x;
#pragma unroll
    for (int i = 0; i < 4; ++i) {
        const int f = (tid + i * 256) * 4;
        const int w = f >> 6, d = f & 63;
        const us4 val = *(const us4*)&src[base + w * 64 + d];
        tile[w][d] = val.x; tile[w][d + 1] = val.y;
        tile[w][d + 2] = val.z; tile[w][d + 3] = val.w;
    }
    __syncthreads();
#pragma unroll
    for (int i = 0; i < 4; ++i) {
        const int f = (tid + i * 256) * 4;
        const int d = f >> 6, w0 = f & 63;
        us4 o; o.x = tile[w0][d]; o.y = tile[w0 + 1][d];
        o.z = tile[w0 + 2][d]; o.w = tile[w0 + 3][d];
        *(us4*)&dst[base + d * 64 + w0] = o;
    }
}

// ------------- permute: dst[c][w][d][h] = src[c][h][w][d] --------------------
__global__ __launch_bounds__(256) void t_hd_kernel(
    const bf16_t* __restrict__ src, bf16_t* __restrict__ dst)
{
    const int w = blockIdx.x, c = blockIdx.y;
    __shared__ bf16_t tile[64][72];
    const size_t cb = (size_t)c * HWD;
    const int tid = threadIdx.x;
#pragma unroll
    for (int i = 0; i < 4; ++i) {
        const int f = (tid + i * 256) * 4;
        const int h = f >> 6, d0 = f & 63;
        const us4 val = *(const us4*)&src[cb + h * WD + w * 64 + d0];
        tile[h][d0] = val.x; tile[h][d0 + 1] = val.y;
        tile[h][d0 + 2] = val.z; tile[h][d0 + 3] = val.w;
    }
    __syncthreads();
#pragma unroll
    for (int i = 0; i < 4; ++i) {
        const int f = (tid + i * 256) * 4;
        const int d = f >> 6, h0 = f & 63;
        us4 o; o.x = tile[h0][d]; o.y = tile[h0 + 1][d];
        o.z = tile[h0 + 2][d]; o.w = tile[h0 + 3][d];
        *(us4*)&dst[cb + w * WD + d * 64 + h0] = o;
    }
}

// ---------------- shared attention phase (MFMA, in-register softmax) ---------
// (unchanged from R11 passing version)
template<bool MASK>
__device__ __forceinline__ void cc_phase(
    const u16* __restrict__ qp, const u16* __restrict__ kp,
    const u16* __restrict__ vp, const size_t base, const int tid,
    u16 (*Qt)[36], u16 (*Kt)[36], u16 (*Vs)[72], u16 (*PB)[72], f32x4* acc)
{
    const int w  = tid >> 6;       // wave id = column-tile
    const int l  = tid & 63;
    const int lg = l >> 4, lr = l & 15;

    __syncthreads();               // prev-phase PV (Vs/PB reads) done before restage
    // ---- q,k loads ----
    const int c0 = (tid >> 6) * 4;
    const size_t gb = base + (tid & 63);
    us4 qv, kv;
    qv.x = qp[(size_t)(c0 + 0) * HWD + gb];
    qv.y = qp[(size_t)(c0 + 1) * HWD + gb];
    qv.z = qp[(size_t)(c0 + 2) * HWD + gb];
    qv.w = qp[(size_t)(c0 + 3) * HWD + gb];
    kv.x = kp[(size_t)(c0 + 0) * HWD + gb];
    kv.y = kp[(size_t)(c0 + 1) * HWD + gb];
    kv.z = kp[(size_t)(c0 + 2) * HWD + gb];
    kv.w = kp[(size_t)(c0 + 3) * HWD + gb];
    // ---- prefetch V slab into registers (drained before PV) ----
    us4 vreg[8];
#pragma unroll
    for (int i = 0; i < 8; ++i) {
        const int f = (tid + i * 256) * 4;
        vreg[i] = *(const us4*)&vp[(size_t)(f >> 6) * HWD + base + (f & 63)];
    }
    // ---- stage q,k transposed + zero K-pad cols (Vs trashed them) ----
    {
        const int j = tid & 63;
        *(us4*)&Qt[j][c0] = qv;
        *(us4*)&Kt[j][c0] = kv;
        us4 z; z.x = z.y = z.z = z.w = 0;
        *(us4*)&Qt[j][16 + c0] = z;
        *(us4*)&Kt[j][16 + c0] = z;
    }
    __syncthreads();
    // ---- QK^T via MFMA: lane holds E[i = 16ti+4lg+r][j = 16w+lr] ----
    float pv[16];
    {
        const bf16x8 bk = ld8_a8(&Kt[16 * w + lr][8 * lg]);
#pragma unroll
        for (int ti = 0; ti < 4; ++ti) {
            const bf16x8 aq = ld8_a8(&Qt[16 * ti + lr][8 * lg]);
            f32x4 e = {0.f, 0.f, 0.f, 0.f};
            e = __builtin_amdgcn_mfma_f32_16x16x32_bf16(aq, bk, e, 0, 0, 0);
#pragma unroll
            for (int r = 0; r < 4; ++r) {
                float vv = e[r];
                if (MASK && (16 * ti + 4 * lg + r) == (16 * w + lr)) vv = -1e30f;
                pv[ti * 4 + r] = vv;
            }
        }
    }
    __syncthreads();               // all waves' Qt/Kt reads done before Vs drain
    // ---- in-register column softmax (across the 4 lg-lanes of column j) ----
    {
        float m = -1e30f;
#pragma unroll
        for (int t = 0; t < 16; ++t) m = fmaxf(m, pv[t]);
        m = fmaxf(m, __shfl_xor(m, 16));
        m = fmaxf(m, __shfl_xor(m, 32));
        float ss = 0.f;
#pragma unroll
        for (int t = 0; t < 16; ++t) { pv[t] = __expf(pv[t] - m); ss += pv[t]; }
        ss += __shfl_xor(ss, 16);
        ss += __shfl_xor(ss, 32);
        const float inv = 1.f / ss;
        // store P[i][j] UNTRANSPOSED: lane's column j, rows i = 16ti+4lg+r.
        const int j = 16 * w + lr;
#pragma unroll
        for (int ti = 0; ti < 4; ++ti)
#pragma unroll
            for (int r = 0; r < 4; ++r)
                PB[16 * ti + 4 * lg + r][j] = f2b(pv[ti * 4 + r] * inv);
    }
    // ---- drain V prefetch into LDS (overlays Qt/Kt; QK reads barriered) ----
#pragma unroll
    for (int i = 0; i < 8; ++i) {
        const int f = (tid + i * 256) * 4;
        *(us4*)&Vs[f >> 6][f & 63] = vreg[i];
    }
    __syncthreads();               // Vs + cross-wave PB ready
    // ---- PV via MFMA: acc[tm] -> C[c = 16tm+4lg+r][dd = 16w+lr] ----
#pragma unroll
    for (int ks = 0; ks < 2; ++ks) {
        const bf16x8 bp = ld8_a16(&PB[16 * w + lr][32 * ks + 8 * lg]);
#pragma unroll
        for (int tm = 0; tm < 8; ++tm) {
            const bf16x8 av = ld8_a16(&Vs[16 * tm + lr][32 * ks + 8 * lg]);
            acc[tm] = __builtin_amdgcn_mfma_f32_16x16x32_bf16(av, bp, acc[tm], 0, 0, 0);
        }
    }
}

// ---------------- fused W+D attention: block (s=bx, hh=by) -------------------
__global__ __launch_bounds__(256, 4) void cc_wd_kernel(
    const bf16_t* __restrict__ q,  const bf16_t* __restrict__ k,
    const bf16_t* __restrict__ v,
    const bf16_t* __restrict__ qT, const bf16_t* __restrict__ kT,
    const bf16_t* __restrict__ vT,
    const float* __restrict__ x, const float* __restrict__ gamma,
    float* __restrict__ out)
{
    const int s   = blockIdx.x;
    const int hh  = blockIdx.y;
    const int tid = threadIdx.x;
    __shared__ __align__(16) u16 VsU[128][72];           // Qt/Kt overlay head
    __shared__ __align__(16) u16 PB[64][72];
    u16 (*Qt)[36] = (u16(*)[36])&VsU[0][0];
    u16 (*Kt)[36] = (u16(*)[36])((u16*)&VsU[0][0] + 64 * 36);
    u16 (*Vs)[72] = VsU;
    f32x4 acc[8];
#pragma unroll
    for (int i = 0; i < 8; ++i) acc[i] = (f32x4){0.f, 0.f, 0.f, 0.f};

    const size_t base = (size_t)hh * WD + s * 64;
    for (int phase = 0; phase < 2; ++phase) {
        const u16* qp = phase ? q : qT;
        const u16* kp = phase ? k : kT;
        const u16* vp = phase ? v : vT;
        cc_phase<false>(qp, kp, vp, base, tid, Qt, Kt, Vs, PB, acc);
    }

    const int w = tid >> 6, l = tid & 63, lg = l >> 4, lr = l & 15;
    const int dd = 16 * w + lr;
    const float g = gamma[0];
#pragma unroll
    for (int tm = 0; tm < 8; ++tm)
#pragma unroll
        for (int r = 0; r < 4; ++r) {
            const int c = 16 * tm + 4 * lg + r;
            const size_t o = (size_t)(2 * s + (c >> 6)) * HWD +
                             (size_t)hh * WD + (size_t)(c & 63) * 64 + dd;
            out[o] = g * acc[tm][r] + x[o];
        }
}

// ---------------- fused H attention: block (t=bx, ww=by) ---------------------
__global__ __launch_bounds__(256, 4) void cc_h_kernel(
    const bf16_t* __restrict__ qH, const bf16_t* __restrict__ kH,
    const bf16_t* __restrict__ vH,
    const float* __restrict__ gamma, float* __restrict__ out)
{
    const int t   = blockIdx.x;
    const int ww  = blockIdx.y;
    const int tid = threadIdx.x;
    __shared__ __align__(16) u16 VsU[128][72];
    __shared__ __align__(16) u16 PB[64][72];
    u16 (*Qt)[36] = (u16(*)[36])&VsU[0][0];
    u16 (*Kt)[36] = (u16(*)[36])((u16*)&VsU[0][0] + 64 * 36);
    u16 (*Vs)[72] = VsU;
    f32x4 acc[8];
#pragma unroll
    for (int i = 0; i < 8; ++i) acc[i] = (f32x4){0.f, 0.f, 0.f, 0.f};

    const size_t base = (size_t)ww * WD + t * 64;
    cc_phase<true>(qH, kH, vH, base, tid, Qt, Kt, Vs, PB, acc);

    const int w = tid >> 6, l = tid & 63, lg = l >> 4, lr = l & 15;
    const int dd = 16 * w + lr;
    const float g = gamma[0];
#pragma unroll
    for (int tm = 0; tm < 8; ++tm)
#pragma unroll
        for (int r = 0; r < 4; ++r) {
            const int c = 16 * tm + 4 * lg + r;
            const size_t o = (size_t)(2 * t + (c >> 6)) * HWD +
                             (size_t)(c & 63) * WD + (size_t)ww * 64 + dd;
            out[o] += g * acc[tm][r];
        }
}

extern "C" void kernel_launch(void* const* d_in, const int* in_sizes, int n_in,
                              void* d_out, int out_size, void* d_ws, size_t ws_size,
                              hipStream_t stream)
{
    const float* x     = (const float*)d_in[0];
    const float* y     = (const float*)d_in[1];
    const float* Wq    = (const float*)d_in[2];
    const float* bq    = (const float*)d_in[3];
    const float* Wk    = (const float*)d_in[4];
    const float* bk    = (const float*)d_in[5];
    const float* Wv    = (const float*)d_in[6];
    const float* bv    = (const float*)d_in[7];
    const float* gamma = (const float*)d_in[8];
    float* out = (float*)d_out;

    // ws layout (bf16): A0 = [v(128ch)|q(16)|k(16)], A1 = wd-transposed,
    // A2 = hd-permuted. Total 240 MiB. Weight fragments (80 KiB, transient)
    // at the HEAD OF A1: prep_w writes, conv reads, t_wd overwrites.
    bf16_t* A0 = (bf16_t*)d_ws;
    bf16_t* v  = A0;
    bf16_t* q  = A0 + (size_t)128 * HWD;
    bf16_t* k  = A0 + (size_t)144 * HWD;
    bf16_t* A1 = A0 + (size_t)160 * HWD;
    bf16_t* A2 = A1 + (size_t)160 * HWD;
    u16* WSv = (u16*)A1;                         // 128*4*2*32 = 32768 u16
    u16* WSq = WSv + 32768;                      // 16*4*2*32  = 4096 u16
    u16* WSk = WSq + 4096;                       // 4096 u16

    prep_w_kernel<<<1, 640, 0, stream>>>(Wv, Wq, Wk, WSv, WSq, WSk);
    conv_x_mfma <<<1024, 512, 0, stream>>>(x, WSv, WSq, bv, bq, v, q);
    conv_y_mfma <<<1024, 256, 0, stream>>>(y, WSk, bk, k);
    t_wd_kernel <<<dim3(64, 160), 256, 0, stream>>>(A0, A1);
    t_hd_kernel <<<dim3(64, 160), 256, 0, stream>>>(A0, A2);
    cc_wd_kernel<<<dim3(64, 64), 256, 0, stream>>>(
        q, k, v, A1 + (size_t)128 * HWD, A1 + (size_t)144 * HWD, A1, x, gamma, out);
    cc_h_kernel <<<dim3(64, 64), 256, 0, stream>>>(
        A2 + (size_t)128 * HWD, A2 + (size_t)144 * HWD, A2, gamma, out);
}

// Round 15
// 543.675 us; speedup vs baseline: 1.1772x; 1.1772x over previous
//
#include <hip/hip_runtime.h>

#define HWD 262144   // H*W*D
#define WD  4096     // W*D

typedef unsigned short bf16_t;
typedef unsigned short u16;
struct __align__(8) us4 { unsigned short x, y, z, w; };

typedef __bf16 bf16x8 __attribute__((ext_vector_type(8)));
typedef float  f32x4  __attribute__((ext_vector_type(4)));

__device__ inline float b2f(unsigned short u) {
    return __uint_as_float(((unsigned int)u) << 16);
}
__device__ inline unsigned short f2b(float f) {
    unsigned int u = __float_as_uint(f);
    u += 0x7fff + ((u >> 16) & 1);          // round-to-nearest-even
    return (unsigned short)(u >> 16);
}

union FragU { us4 h[2]; bf16x8 v; };
__device__ inline bf16x8 ld8_a8(const u16* p) {   // 8B-aligned source
    FragU f; f.h[0] = *(const us4*)p; f.h[1] = *(const us4*)(p + 4); return f.v;
}
__device__ inline bf16x8 ld8_a16(const u16* p) {  // 16B-aligned source
    return *(const bf16x8*)p;
}

// -------- one-time weight hi/lo split into MFMA-fragment layout --------------
__global__ void prep_w_kernel(
    const float* __restrict__ Wv, const float* __restrict__ Wq,
    const float* __restrict__ Wk,
    u16* __restrict__ WSv, u16* __restrict__ WSq, u16* __restrict__ WSk)
{
    const int t = threadIdx.x;
    const float* W; u16* D; int m, ks;
    if (t < 512)      { W = Wv; D = WSv; m = t >> 2;          ks = t & 3; }
    else if (t < 576) { W = Wq; D = WSq; m = (t - 512) >> 2;  ks = t & 3; }
    else if (t < 640) { W = Wk; D = WSk; m = (t - 576) >> 2;  ks = t & 3; }
    else return;
#pragma unroll
    for (int j = 0; j < 32; ++j) {
        const float w = W[m * 128 + ks * 32 + j];
        const u16 h = f2b(w);
        const u16 l = f2b(w - b2f(h));          // Sterbenz-exact residual
        D[((m * 4 + ks) * 2 + 0) * 32 + j] = h;
        D[((m * 4 + ks) * 2 + 1) * 32 + j] = l;
    }
}

// -------- v = Wv·x + bv AND q = Wq·x + bq in ONE pass over x -----------------
// IDENTICAL math to R11. Staging loads widened: 4x float4/thread (16B/lane),
// each instruction covers 4 full 256B channel rows contiguously — wide loads
// stay co-live in VGPRs (real MLP), unlike 16 scalar dwords.
__global__ __launch_bounds__(512, 4) void conv_x_mfma(
    const float* __restrict__ x, const u16* __restrict__ WSv,
    const u16* __restrict__ WSq,
    const float* __restrict__ bv, const float* __restrict__ bq,
    bf16_t* __restrict__ v, bf16_t* __restrict__ q)
{
    __shared__ __align__(16) u16 Xh[64][136];   // [n][k]
    __shared__ __align__(16) u16 Xl[64][136];
    const int tid  = threadIdx.x;
    const int lane = tid & 63;
    const int wv   = tid >> 6;                 // wave 0..7
    const int lg = lane >> 4, lr = lane & 15;
    const int n0 = blockIdx.x * 64;
    const int m0 = wv * 16;

    // ---- wide staging loads: lane's 16B chunk of 4 different channel rows --
    const int ng = (lane & 15) * 4;            // n-offset of this 16B chunk
    float4 L[4];
#pragma unroll
    for (int j = 0; j < 4; ++j) {
        const int c = wv * 16 + (lane >> 4) * 4 + j;
        L[j] = *(const float4*)&x[(size_t)c * HWD + n0 + ng];
    }

    // ---- A-frags: direct 16B loads of pre-split weights ----
    bf16x8 Ah[4], Al[4], Qh[4], Ql[4];
#pragma unroll
    for (int ks = 0; ks < 4; ++ks) {
        Ah[ks] = ld8_a16(&WSv[(((m0 + lr) * 4 + ks) * 2 + 0) * 32 + lg * 8]);
        Al[ks] = ld8_a16(&WSv[(((m0 + lr) * 4 + ks) * 2 + 1) * 32 + lg * 8]);
    }
    if (wv < 4) {
#pragma unroll
        for (int ks = 0; ks < 4; ++ks) {
            Qh[ks] = ld8_a16(&WSq[((lr * 4 + ks) * 2 + 0) * 32 + lg * 8]);
            Ql[ks] = ld8_a16(&WSq[((lr * 4 + ks) * 2 + 1) * 32 + lg * 8]);
        }
    }

    // ---- split + stage (per-element identical to split8: h=f2b(v), l=f2b(v-h))
#pragma unroll
    for (int j = 0; j < 4; ++j) {
        const int c = wv * 16 + (lane >> 4) * 4 + j;
        const float e4[4] = {L[j].x, L[j].y, L[j].z, L[j].w};
#pragma unroll
        for (int e = 0; e < 4; ++e) {
            const u16 h  = f2b(e4[e]);
            const u16 lo = f2b(e4[e] - b2f(h));
            Xh[ng + e][c] = h;
            Xl[ng + e][c] = lo;
        }
    }
    __syncthreads();

    f32x4 acc[4];
#pragma unroll
    for (int ns = 0; ns < 4; ++ns) acc[ns] = (f32x4){0.f, 0.f, 0.f, 0.f};
    f32x4 accq = (f32x4){0.f, 0.f, 0.f, 0.f};
#pragma unroll
    for (int ks = 0; ks < 4; ++ks) {
#pragma unroll
        for (int ns = 0; ns < 4; ++ns) {
            const bf16x8 Bh = ld8_a16(&Xh[ns * 16 + lr][ks * 32 + lg * 8]);
            const bf16x8 Bl = ld8_a16(&Xl[ns * 16 + lr][ks * 32 + lg * 8]);
            acc[ns] = __builtin_amdgcn_mfma_f32_16x16x32_bf16(Ah[ks], Bh, acc[ns], 0, 0, 0);
            acc[ns] = __builtin_amdgcn_mfma_f32_16x16x32_bf16(Ah[ks], Bl, acc[ns], 0, 0, 0);
            acc[ns] = __builtin_amdgcn_mfma_f32_16x16x32_bf16(Al[ks], Bh, acc[ns], 0, 0, 0);
            if (wv < 4 && ns == wv) {
                accq = __builtin_amdgcn_mfma_f32_16x16x32_bf16(Qh[ks], Bh, accq, 0, 0, 0);
                accq = __builtin_amdgcn_mfma_f32_16x16x32_bf16(Qh[ks], Bl, accq, 0, 0, 0);
                accq = __builtin_amdgcn_mfma_f32_16x16x32_bf16(Ql[ks], Bh, accq, 0, 0, 0);
            }
        }
    }
#pragma unroll
    for (int ns = 0; ns < 4; ++ns)
#pragma unroll
        for (int r = 0; r < 4; ++r) {
            const int m = m0 + 4 * lg + r;
            v[(size_t)m * HWD + n0 + ns * 16 + lr] = f2b(acc[ns][r] + bv[m]);
        }
    if (wv < 4) {
#pragma unroll
        for (int r = 0; r < 4; ++r) {
            const int m = 4 * lg + r;
            q[(size_t)m * HWD + n0 + wv * 16 + lr] = f2b(accq[r] + bq[m]);
        }
    }
}

// -------- k = Wk·y + bk (M=16; staging widened to 8x float4/thread) ----------
__global__ __launch_bounds__(256, 4) void conv_y_mfma(
    const float* __restrict__ y, const u16* __restrict__ WSk,
    const float* __restrict__ bk, bf16_t* __restrict__ k)
{
    __shared__ __align__(16) u16 Yh[64][136];
    __shared__ __align__(16) u16 Yl[64][136];
    const int tid  = threadIdx.x;
    const int lane = tid & 63;
    const int wv   = tid >> 6;                // 0..3 = n-subtile
    const int lg = lane >> 4, lr = lane & 15;
    const int n0 = blockIdx.x * 64;

    const int ng = (lane & 15) * 4;
    float4 L[8];
#pragma unroll
    for (int j = 0; j < 8; ++j) {
        const int c = wv * 32 + (lane >> 4) * 8 + j;
        L[j] = *(const float4*)&y[(size_t)c * HWD + n0 + ng];
    }

    bf16x8 Ah[4], Al[4];
#pragma unroll
    for (int ks = 0; ks < 4; ++ks) {
        Ah[ks] = ld8_a16(&WSk[((lr * 4 + ks) * 2 + 0) * 32 + lg * 8]);
        Al[ks] = ld8_a16(&WSk[((lr * 4 + ks) * 2 + 1) * 32 + lg * 8]);
    }

#pragma unroll
    for (int j = 0; j < 8; ++j) {
        const int c = wv * 32 + (lane >> 4) * 8 + j;
        const float e4[4] = {L[j].x, L[j].y, L[j].z, L[j].w};
#pragma unroll
        for (int e = 0; e < 4; ++e) {
            const u16 h  = f2b(e4[e]);
            const u16 lo = f2b(e4[e] - b2f(h));
            Yh[ng + e][c] = h;
            Yl[ng + e][c] = lo;
        }
    }
    __syncthreads();

    f32x4 acc = (f32x4){0.f, 0.f, 0.f, 0.f};
#pragma unroll
    for (int ks = 0; ks < 4; ++ks) {
        const bf16x8 Bh = ld8_a16(&Yh[wv * 16 + lr][ks * 32 + lg * 8]);
        const bf16x8 Bl = ld8_a16(&Yl[wv * 16 + lr][ks * 32 + lg * 8]);
        acc = __builtin_amdgcn_mfma_f32_16x16x32_bf16(Ah[ks], Bh, acc, 0, 0, 0);
        acc = __builtin_amdgcn_mfma_f32_16x16x32_bf16(Ah[ks], Bl, acc, 0, 0, 0);
        acc = __builtin_amdgcn_mfma_f32_16x16x32_bf16(Al[ks], Bh, acc, 0, 0, 0);
    }
#pragma unroll
    for (int r = 0; r < 4; ++r) {
        const int m = 4 * lg + r;
        k[(size_t)m * HWD + n0 + wv * 16 + lr] = f2b(acc[r] + bk[m]);
    }
}

// ------------- transpose (w<->d): dst[c][h][d][w] = src[c][h][w][d] ----------
__global__ __launch_bounds__(256) void t_wd_kernel(
    const bf16_t* __restrict__ src, bf16_t* __restrict__ dst)
{
    const int h = blockIdx.x, c = blockIdx.y;
    __shared__ bf16_t tile[64][68];
    const size_t base = (size_t)c * HWD + h * WD;
    const int tid = threadIdx.x;
#pragma unroll
    for (int i = 0; i < 4; ++i) {
        const int f = (tid + i * 256) * 4;
        const int w = f >> 6, d = f & 63;
        const us4 val = *(const us4*)&src[base + w * 64 + d];
        tile[w][d] = val.x; tile[w][d + 1] = val.y;
        tile[w][d + 2] = val.z; tile[w][d + 3] = val.w;
    }
    __syncthreads();
#pragma unroll
    for (int i = 0; i < 4; ++i) {
        const int f = (tid + i * 256) * 4;
        const int d = f >> 6, w0 = f & 63;
        us4 o; o.x = tile[w0][d]; o.y = tile[w0 + 1][d];
        o.z = tile[w0 + 2][d]; o.w = tile[w0 + 3][d];
        *(us4*)&dst[base + d * 64 + w0] = o;
    }
}

// ------------- permute: dst[c][w][d][h] = src[c][h][w][d] --------------------
__global__ __launch_bounds__(256) void t_hd_kernel(
    const bf16_t* __restrict__ src, bf16_t* __restrict__ dst)
{
    const int w = blockIdx.x, c = blockIdx.y;
    __shared__ bf16_t tile[64][68];
    const size_t cb = (size_t)c * HWD;
    const int tid = threadIdx.x;
#pragma unroll
    for (int i = 0; i < 4; ++i) {
        const int f = (tid + i * 256) * 4;
        const int h = f >> 6, d0 = f & 63;
        const us4 val = *(const us4*)&src[cb + h * WD + w * 64 + d0];
        tile[h][d0] = val.x; tile[h][d0 + 1] = val.y;
        tile[h][d0 + 2] = val.z; tile[h][d0 + 3] = val.w;
    }
    __syncthreads();
#pragma unroll
    for (int i = 0; i < 4; ++i) {
        const int f = (tid + i * 256) * 4;
        const int d = f >> 6, h0 = f & 63;
        us4 o; o.x = tile[h0][d]; o.y = tile[h0 + 1][d];
        o.z = tile[h0 + 2][d]; o.w = tile[h0 + 3][d];
        *(us4*)&dst[cb + w * WD + d * 64 + h0] = o;
    }
}

// ---------------- shared attention phase (MFMA, in-register softmax) ---------
// (unchanged from R11 passing version)
template<bool MASK>
__device__ __forceinline__ void cc_phase(
    const u16* __restrict__ qp, const u16* __restrict__ kp,
    const u16* __restrict__ vp, const size_t base, const int tid,
    u16 (*Qt)[36], u16 (*Kt)[36], u16 (*Vs)[72], u16 (*PB)[72], f32x4* acc)
{
    const int w  = tid >> 6;       // wave id = column-tile
    const int l  = tid & 63;
    const int lg = l >> 4, lr = l & 15;

    __syncthreads();               // prev-phase PV (Vs/PB reads) done before restage
    // ---- q,k loads ----
    const int c0 = (tid >> 6) * 4;
    const size_t gb = base + (tid & 63);
    us4 qv, kv;
    qv.x = qp[(size_t)(c0 + 0) * HWD + gb];
    qv.y = qp[(size_t)(c0 + 1) * HWD + gb];
    qv.z = qp[(size_t)(c0 + 2) * HWD + gb];
    qv.w = qp[(size_t)(c0 + 3) * HWD + gb];
    kv.x = kp[(size_t)(c0 + 0) * HWD + gb];
    kv.y = kp[(size_t)(c0 + 1) * HWD + gb];
    kv.z = kp[(size_t)(c0 + 2) * HWD + gb];
    kv.w = kp[(size_t)(c0 + 3) * HWD + gb];
    // ---- prefetch V slab into registers (drained before PV) ----
    us4 vreg[8];
#pragma unroll
    for (int i = 0; i < 8; ++i) {
        const int f = (tid + i * 256) * 4;
        vreg[i] = *(const us4*)&vp[(size_t)(f >> 6) * HWD + base + (f & 63)];
    }
    // ---- stage q,k transposed + zero K-pad cols (Vs trashed them) ----
    {
        const int j = tid & 63;
        *(us4*)&Qt[j][c0] = qv;
        *(us4*)&Kt[j][c0] = kv;
        us4 z; z.x = z.y = z.z = z.w = 0;
        *(us4*)&Qt[j][16 + c0] = z;
        *(us4*)&Kt[j][16 + c0] = z;
    }
    __syncthreads();
    // ---- QK^T via MFMA: lane holds E[i = 16ti+4lg+r][j = 16w+lr] ----
    float pv[16];
    {
        const bf16x8 bk = ld8_a8(&Kt[16 * w + lr][8 * lg]);
#pragma unroll
        for (int ti = 0; ti < 4; ++ti) {
            const bf16x8 aq = ld8_a8(&Qt[16 * ti + lr][8 * lg]);
            f32x4 e = {0.f, 0.f, 0.f, 0.f};
            e = __builtin_amdgcn_mfma_f32_16x16x32_bf16(aq, bk, e, 0, 0, 0);
#pragma unroll
            for (int r = 0; r < 4; ++r) {
                float vv = e[r];
                if (MASK && (16 * ti + 4 * lg + r) == (16 * w + lr)) vv = -1e30f;
                pv[ti * 4 + r] = vv;
            }
        }
    }
    __syncthreads();               // all waves' Qt/Kt reads done before Vs drain
    // ---- in-register column softmax (across the 4 lg-lanes of column j) ----
    {
        float m = -1e30f;
#pragma unroll
        for (int t = 0; t < 16; ++t) m = fmaxf(m, pv[t]);
        m = fmaxf(m, __shfl_xor(m, 16));
        m = fmaxf(m, __shfl_xor(m, 32));
        float ss = 0.f;
#pragma unroll
        for (int t = 0; t < 16; ++t) { pv[t] = __expf(pv[t] - m); ss += pv[t]; }
        ss += __shfl_xor(ss, 16);
        ss += __shfl_xor(ss, 32);
        const float inv = 1.f / ss;
        // store P[i][j] UNTRANSPOSED: lane's column j, rows i = 16ti+4lg+r.
        const int j = 16 * w + lr;
#pragma unroll
        for (int ti = 0; ti < 4; ++ti)
#pragma unroll
            for (int r = 0; r < 4; ++r)
                PB[16 * ti + 4 * lg + r][j] = f2b(pv[ti * 4 + r] * inv);
    }
    // ---- drain V prefetch into LDS (overlays Qt/Kt; QK reads barriered) ----
#pragma unroll
    for (int i = 0; i < 8; ++i) {
        const int f = (tid + i * 256) * 4;
        *(us4*)&Vs[f >> 6][f & 63] = vreg[i];
    }
    __syncthreads();               // Vs + cross-wave PB ready
    // ---- PV via MFMA: acc[tm] -> C[c = 16tm+4lg+r][dd = 16w+lr] ----
#pragma unroll
    for (int ks = 0; ks < 2; ++ks) {
        const bf16x8 bp = ld8_a16(&PB[16 * w + lr][32 * ks + 8 * lg]);
#pragma unroll
        for (int tm = 0; tm < 8; ++tm) {
            const bf16x8 av = ld8_a16(&Vs[16 * tm + lr][32 * ks + 8 * lg]);
            acc[tm] = __builtin_amdgcn_mfma_f32_16x16x32_bf16(av, bp, acc[tm], 0, 0, 0);
        }
    }
}

// ---------------- fused W+D attention: block (s=bx, hh=by) -------------------
__global__ __launch_bounds__(256, 4) void cc_wd_kernel(
    const bf16_t* __restrict__ q,  const bf16_t* __restrict__ k,
    const bf16_t* __restrict__ v,
    const bf16_t* __restrict__ qT, const bf16_t* __restrict__ kT,
    const bf16_t* __restrict__ vT,
    const float* __restrict__ x, const float* __restrict__ gamma,
    float* __restrict__ out)
{
    const int s   = blockIdx.x;
    const int hh  = blockIdx.y;
    const int tid = threadIdx.x;
    __shared__ __align__(16) u16 VsU[128][72];           // Qt/Kt overlay head
    __shared__ __align__(16) u16 PB[64][72];
    u16 (*Qt)[36] = (u16(*)[36])&VsU[0][0];
    u16 (*Kt)[36] = (u16(*)[36])((u16*)&VsU[0][0] + 64 * 36);
    u16 (*Vs)[72] = VsU;
    f32x4 acc[8];
#pragma unroll
    for (int i = 0; i < 8; ++i) acc[i] = (f32x4){0.f, 0.f, 0.f, 0.f};

    const size_t base = (size_t)hh * WD + s * 64;
    for (int phase = 0; phase < 2; ++phase) {
        const u16* qp = phase ? q : qT;
        const u16* kp = phase ? k : kT;
        const u16* vp = phase ? v : vT;
        cc_phase<false>(qp, kp, vp, base, tid, Qt, Kt, Vs, PB, acc);
    }

    const int w = tid >> 6, l = tid & 63, lg = l >> 4, lr = l & 15;
    const int dd = 16 * w + lr;
    const float g = gamma[0];
#pragma unroll
    for (int tm = 0; tm < 8; ++tm)
#pragma unroll
        for (int r = 0; r < 4; ++r) {
            const int c = 16 * tm + 4 * lg + r;
            const size_t o = (size_t)(2 * s + (c >> 6)) * HWD +
                             (size_t)hh * WD + (size_t)(c & 63) * 64 + dd;
            out[o] = g * acc[tm][r] + x[o];
        }
}

// ---------------- fused H attention: block (t=bx, ww=by) ---------------------
__global__ __launch_bounds__(256, 4) void cc_h_kernel(
    const bf16_t* __restrict__ qH, const bf16_t* __restrict__ kH,
    const bf16_t* __restrict__ vH,
    const float* __restrict__ gamma, float* __restrict__ out)
{
    const int t   = blockIdx.x;
    const int ww  = blockIdx.y;
    const int tid = threadIdx.x;
    __shared__ __align__(16) u16 VsU[128][72];
    __shared__ __align__(16) u16 PB[64][72];
    u16 (*Qt)[36] = (u16(*)[36])&VsU[0][0];
    u16 (*Kt)[36] = (u16(*)[36])((u16*)&VsU[0][0] + 64 * 36);
    u16 (*Vs)[72] = VsU;
    f32x4 acc[8];
#pragma unroll
    for (int i = 0; i < 8; ++i) acc[i] = (f32x4){0.f, 0.f, 0.f, 0.f};

    const size_t base = (size_t)ww * WD + t * 64;
    cc_phase<true>(qH, kH, vH, base, tid, Qt, Kt, Vs, PB, acc);

    const int w = tid >> 6, l = tid & 63, lg = l >> 4, lr = l & 15;
    const int dd = 16 * w + lr;
    const float g = gamma[0];
#pragma unroll
    for (int tm = 0; tm < 8; ++tm)
#pragma unroll
        for (int r = 0; r < 4; ++r) {
            const int c = 16 * tm + 4 * lg + r;
            const size_t o = (size_t)(2 * t + (c >> 6)) * HWD +
                             (size_t)(c & 63) * WD + (size_t)ww * 64 + dd;
            out[o] += g * acc[tm][r];
        }
}

extern "C" void kernel_launch(void* const* d_in, const int* in_sizes, int n_in,
                              void* d_out, int out_size, void* d_ws, size_t ws_size,
                              hipStream_t stream)
{
    const float* x     = (const float*)d_in[0];
    const float* y     = (const float*)d_in[1];
    const float* Wq    = (const float*)d_in[2];
    const float* bq    = (const float*)d_in[3];
    const float* Wk    = (const float*)d_in[4];
    const float* bk    = (const float*)d_in[5];
    const float* Wv    = (const float*)d_in[6];
    const float* bv    = (const float*)d_in[7];
    const float* gamma = (const float*)d_in[8];
    float* out = (float*)d_out;

    // ws layout (bf16): A0 = [v(128ch)|q(16)|k(16)], A1 = wd-transposed,
    // A2 = hd-permuted. Total 240 MiB. Weight fragments (80 KiB, transient)
    // at the HEAD OF A1: prep_w writes, conv reads, t_wd overwrites.
    bf16_t* A0 = (bf16_t*)d_ws;
    bf16_t* v  = A0;
    bf16_t* q  = A0 + (size_t)128 * HWD;
    bf16_t* k  = A0 + (size_t)144 * HWD;
    bf16_t* A1 = A0 + (size_t)160 * HWD;
    bf16_t* A2 = A1 + (size_t)160 * HWD;
    u16* WSv = (u16*)A1;                         // 128*4*2*32 = 32768 u16
    u16* WSq = WSv + 32768;                      // 16*4*2*32  = 4096 u16
    u16* WSk = WSq + 4096;                       // 4096 u16

    prep_w_kernel<<<1, 640, 0, stream>>>(Wv, Wq, Wk, WSv, WSq, WSk);
    conv_x_mfma <<<4096, 512, 0, stream>>>(x, WSv, WSq, bv, bq, v, q);
    conv_y_mfma <<<4096, 256, 0, stream>>>(y, WSk, bk, k);
    t_wd_kernel <<<dim3(64, 160), 256, 0, stream>>>(A0, A1);
    t_hd_kernel <<<dim3(64, 160), 256, 0, stream>>>(A0, A2);
    cc_wd_kernel<<<dim3(64, 64), 256, 0, stream>>>(
        q, k, v, A1 + (size_t)128 * HWD, A1 + (size_t)144 * HWD, A1, x, gamma, out);
    cc_h_kernel <<<dim3(64, 64), 256, 0, stream>>>(
        A2 + (size_t)128 * HWD, A2 + (size_t)144 * HWD, A2, gamma, out);
}